// Round 4
// baseline (265.298 us; speedup 1.0000x reference)
//
#include <hip/hip_runtime.h>

#define BC 16
#define NN 2048
#define FF 128
#define DD 128
#define NEDGES 65536
#define NEG_INF -1e16f
#define LEAK 0.1f
#define CAPR 128   // per-row in-degree cap; P(Poisson(32) > 128) ~ 1e-35

// ---------------- Kernel 1: z = h @ W (+ zero the adjacency bitmask) -----
__global__ void __launch_bounds__(256) zgemm_kernel(const float* __restrict__ h,
                                                    const float* __restrict__ W,
                                                    float* __restrict__ z,
                                                    unsigned int* __restrict__ mask) {
    const int tid = threadIdx.x;
    const int gid = blockIdx.x * 256 + tid;
    if (gid < NN * NN / 32) mask[gid] = 0u;   // fold memset in (1024*256 >= 131072)

    __shared__ float hs[32][FF];   // 16 KB
    const size_t row0 = (size_t)blockIdx.x * 32;
    const float4* hv = (const float4*)(h + row0 * FF);
    float4* hsv = (float4*)&hs[0][0];
#pragma unroll
    for (int i = 0; i < 4; ++i) hsv[tid + 256 * i] = hv[tid + 256 * i];
    __syncthreads();

    const int c0 = (tid & 31) * 4;
    const int r0 = (tid >> 5) * 4;
    float acc[4][4] = {};
    for (int f = 0; f < FF; f += 4) {
        float4 a[4], bb[4];
#pragma unroll
        for (int r = 0; r < 4; ++r) a[r] = *(const float4*)&hs[r0 + r][f];
#pragma unroll
        for (int k = 0; k < 4; ++k) bb[k] = *(const float4*)&W[(f + k) * DD + c0];
#pragma unroll
        for (int r = 0; r < 4; ++r) {
            acc[r][0] += a[r].x * bb[0].x + a[r].y * bb[1].x + a[r].z * bb[2].x + a[r].w * bb[3].x;
            acc[r][1] += a[r].x * bb[0].y + a[r].y * bb[1].y + a[r].z * bb[2].y + a[r].w * bb[3].y;
            acc[r][2] += a[r].x * bb[0].z + a[r].y * bb[1].z + a[r].z * bb[2].z + a[r].w * bb[3].z;
            acc[r][3] += a[r].x * bb[0].w + a[r].y * bb[1].w + a[r].z * bb[2].w + a[r].w * bb[3].w;
        }
    }
#pragma unroll
    for (int r = 0; r < 4; ++r)
        *(float4*)&z[(row0 + r0 + r) * DD + c0] =
            make_float4(acc[r][0], acc[r][1], acc[r][2], acc[r][3]);
}

// ---------------- Kernel 2: dedup adjacency bitmask ----------------
__global__ void mask_kernel(const int* __restrict__ row, const int* __restrict__ col,
                            unsigned int* __restrict__ mask) {
    const int e = blockIdx.x * blockDim.x + threadIdx.x;
    if (e < NEDGES) {
        const unsigned int key = (unsigned int)row[e] * NN + (unsigned int)col[e];
        atomicOr(&mask[key >> 5], 1u << (key & 31u));
    }
}

// ---------------- Kernel 3: bitmask -> CSR (shared across batches) -------
// one wave per row n: lane reads 1 of 64 mask words, ffs loop, LDS counter.
__global__ void __launch_bounds__(256) csr_kernel(const unsigned int* __restrict__ mask,
                                                  unsigned short* __restrict__ hits_g,
                                                  int* __restrict__ deg) {
    __shared__ int cnt[4];
    const int tid = threadIdx.x, wv = tid >> 6, ln = tid & 63;
    const int n = blockIdx.x * 4 + wv;
    if (ln == 0) cnt[wv] = 0;
    unsigned int bits = mask[n * 64 + ln];
    while (bits) {
        const int bit = __ffs(bits) - 1;
        bits &= bits - 1;
        const int idx = atomicAdd(&cnt[wv], 1);
        if (idx < CAPR) hits_g[n * CAPR + idx] = (unsigned short)(ln * 32 + bit);
    }
    if (ln == 0) deg[n] = cnt[wv];
}

// ---------------- Kernel 4: fused score+softmax+aggregate ----------------
// 4 independent waves per block, one wave per (b,n) row. No barriers.
// b = ((blk&7)<<1)|(wv&1): XCD x (round-robin blk%8) sees only batches
// {2x,2x+1} -> 2 MB of z pinned per 4 MB XCD-L2.
// Lane = (eq,q): eq=edge slot 0..15, q=dim-quarter. Score gather registers
// are REUSED for aggregation (acc = lane's 32-dim slice); cross-edge sum via
// final xor-4/8/16/32 butterfly. z[col] is fetched exactly once per edge.
__global__ void __launch_bounds__(256, 4) gat_kernel(const float* __restrict__ z,
                                                     const unsigned short* __restrict__ hits_g,
                                                     const int* __restrict__ deg,
                                                     float* __restrict__ out) {
    __shared__ unsigned short hl[4][CAPR];   // 1 KB
    const int tid = threadIdx.x, wv = tid >> 6, ln = tid & 63;
    const int blk = blockIdx.x;
    const int b = ((blk & 7) << 1) | (wv & 1);
    const int n = ((blk >> 3) << 1) | (wv >> 1);
    const int eq = ln >> 2, q = ln & 3;

    const float* zb = z + ((size_t)b << 18);
    const int nh = min(deg[n], CAPR);

    // stage hit list; zero the pads so pad gathers stay in-bounds
    for (int i = ln; i < CAPR; i += 64)
        hl[wv][i] = (i < nh) ? hits_g[n * CAPR + i] : (unsigned short)0;

    // this row's z slice (dims q*32 .. q*32+31) in registers (L1 broadcast)
    float4 a[8];
    {
        const float4* znp = (const float4*)(zb + ((size_t)n << 7) + (q << 5));
#pragma unroll
        for (int j = 0; j < 8; ++j) a[j] = znp[j];
    }

    float m = NEG_INF, l = 0.f;
    float4 acc[8];
#pragma unroll
    for (int j = 0; j < 8; ++j) acc[j] = make_float4(0.f, 0.f, 0.f, 0.f);

    for (int c0 = 0; c0 < nh; c0 += 16) {
        const int e = c0 + eq;                       // <= 127 always (c0<=112)
        const int he = hl[wv][e];
        const float4* zc = (const float4*)(zb + ((size_t)he << 7) + (q << 5));
        float4 v[8];
#pragma unroll
        for (int j = 0; j < 8; ++j) v[j] = zc[j];    // 8 lines in flight/lane

        float pt = 0.f;
#pragma unroll
        for (int j = 0; j < 8; ++j)
            pt += a[j].x * v[j].x + a[j].y * v[j].y + a[j].z * v[j].z + a[j].w * v[j].w;
        pt += __shfl_xor(pt, 1, 64);
        pt += __shfl_xor(pt, 2, 64);                 // quad now holds full dot
        float sv = pt > 0.f ? pt : LEAK * pt;        // leaky_relu(0.1)
        if (sv == 0.f || e >= nh) sv = NEG_INF;      // masked_fill / pad

        float mx = sv;
#pragma unroll
        for (int off = 4; off <= 32; off <<= 1) mx = fmaxf(mx, __shfl_xor(mx, off, 64));
        const float mnew = fmaxf(m, mx);
        const float alpha = __expf(m - mnew);        // 1 when both NEG_INF
        const float pr = __expf(sv - mnew);
        float ps = pr;
#pragma unroll
        for (int off = 4; off <= 32; off <<= 1) ps += __shfl_xor(ps, off, 64);
        l = l * alpha + ps;
        m = mnew;
        // aggregate in-register: acc over this lane's 32 dims of edge eq
#pragma unroll
        for (int j = 0; j < 8; ++j) {
            acc[j].x = acc[j].x * alpha + pr * v[j].x;
            acc[j].y = acc[j].y * alpha + pr * v[j].y;
            acc[j].z = acc[j].z * alpha + pr * v[j].z;
            acc[j].w = acc[j].w * alpha + pr * v[j].w;
        }
    }

    if (nh > 0 && m > 0.5f * NEG_INF) {
        // cross-edge reduction: sum acc over the 16 eq-lanes (xor bits 2..5)
#pragma unroll
        for (int off = 4; off <= 32; off <<= 1) {
#pragma unroll
            for (int j = 0; j < 8; ++j) {
                acc[j].x += __shfl_xor(acc[j].x, off, 64);
                acc[j].y += __shfl_xor(acc[j].y, off, 64);
                acc[j].z += __shfl_xor(acc[j].z, off, 64);
                acc[j].w += __shfl_xor(acc[j].w, off, 64);
            }
        }
        const float inv = 1.f / l;
#pragma unroll
        for (int j = 0; j < 8; ++j) {
            acc[j].x *= inv; acc[j].y *= inv; acc[j].z *= inv; acc[j].w *= inv;
        }
    } else {
        // no valid edge: softmax over uniform -1e16 row -> mean of z[b]
#pragma unroll
        for (int j = 0; j < 8; ++j) acc[j] = make_float4(0.f, 0.f, 0.f, 0.f);
        for (int mm = 0; mm < NN; ++mm) {
            const float4* zr = (const float4*)(zb + ((size_t)mm << 7) + (q << 5));
#pragma unroll
            for (int j = 0; j < 8; ++j) {
                float4 t = zr[j];
                acc[j].x += t.x; acc[j].y += t.y; acc[j].z += t.z; acc[j].w += t.w;
            }
        }
#pragma unroll
        for (int j = 0; j < 8; ++j) {
            acc[j].x *= (1.f / NN); acc[j].y *= (1.f / NN);
            acc[j].z *= (1.f / NN); acc[j].w *= (1.f / NN);
        }
    }

    // store: lanes eq<8 write one float4 each -> 512 B coalesced per row
    if (eq < 8) {
        float4 o;
#pragma unroll
        for (int j = 0; j < 8; ++j) if (eq == j) o = acc[j];
        *(float4*)(out + (((size_t)b * NN + n) << 7) + (q << 5) + (eq << 2)) = o;
    }
}

// ---------------- launcher ----------------
extern "C" void kernel_launch(void* const* d_in, const int* in_sizes, int n_in,
                              void* d_out, int out_size, void* d_ws, size_t ws_size,
                              hipStream_t stream) {
    const float* h = (const float*)d_in[0];
    const float* W = (const float*)d_in[1];
    const int* row = (const int*)d_in[2];
    const int* col = (const int*)d_in[3];
    float* out = (float*)d_out;

    char* ws = (char*)d_ws;
    float* z = (float*)ws;                                        // 16 MB
    unsigned int* mask = (unsigned int*)(ws + (size_t)16 * 1024 * 1024);      // 512 KB
    unsigned short* hits_g = (unsigned short*)(ws + (size_t)16 * 1024 * 1024 + 512 * 1024); // 512 KB
    int* deg = (int*)(ws + (size_t)17 * 1024 * 1024);             // 8 KB

    zgemm_kernel<<<(BC * NN) / 32, 256, 0, stream>>>(h, W, z, mask);
    mask_kernel<<<NEDGES / 256, 256, 0, stream>>>(row, col, mask);
    csr_kernel<<<NN / 4, 256, 0, stream>>>(mask, hits_g, deg);
    gat_kernel<<<(BC * NN) / 4, 256, 0, stream>>>(z, hits_g, deg, out);
}

// Round 5
// 172.174 us; speedup vs baseline: 1.5409x; 1.5409x over previous
//
#include <hip/hip_runtime.h>

#define BC 16
#define NN 2048
#define FF 128
#define DD 128
#define NEDGES 65536
#define NEG_INF -1e16f
#define LEAK 0.1f
#define CAPR 128   // per-row in-degree cap; P(Poisson(32) > 128) ~ 1e-35

// ---------------- Kernel 1: z = h @ W (+ zero mask & deg) ----------------
__global__ void __launch_bounds__(256) zgemm_kernel(const float* __restrict__ h,
                                                    const float* __restrict__ W,
                                                    float* __restrict__ z,
                                                    unsigned int* __restrict__ mask,
                                                    int* __restrict__ deg) {
    const int tid = threadIdx.x;
    const int gid = blockIdx.x * 256 + tid;
    if (gid < NN * NN / 32) mask[gid] = 0u;   // 1024*256 = 262144 >= 131072
    if (gid < NN) deg[gid] = 0;

    __shared__ float hs[32][FF];   // 16 KB
    const size_t row0 = (size_t)blockIdx.x * 32;
    const float4* hv = (const float4*)(h + row0 * FF);
    float4* hsv = (float4*)&hs[0][0];
#pragma unroll
    for (int i = 0; i < 4; ++i) hsv[tid + 256 * i] = hv[tid + 256 * i];
    __syncthreads();

    const int c0 = (tid & 31) * 4;
    const int r0 = (tid >> 5) * 4;
    float acc[4][4] = {};
    for (int f = 0; f < FF; f += 4) {
        float4 a[4], bb[4];
#pragma unroll
        for (int r = 0; r < 4; ++r) a[r] = *(const float4*)&hs[r0 + r][f];
#pragma unroll
        for (int k = 0; k < 4; ++k) bb[k] = *(const float4*)&W[(f + k) * DD + c0];
#pragma unroll
        for (int r = 0; r < 4; ++r) {
            acc[r][0] += a[r].x * bb[0].x + a[r].y * bb[1].x + a[r].z * bb[2].x + a[r].w * bb[3].x;
            acc[r][1] += a[r].x * bb[0].y + a[r].y * bb[1].y + a[r].z * bb[2].y + a[r].w * bb[3].y;
            acc[r][2] += a[r].x * bb[0].z + a[r].y * bb[1].z + a[r].z * bb[2].z + a[r].w * bb[3].z;
            acc[r][3] += a[r].x * bb[0].w + a[r].y * bb[1].w + a[r].z * bb[2].w + a[r].w * bb[3].w;
        }
    }
#pragma unroll
    for (int r = 0; r < 4; ++r)
        *(float4*)&z[(row0 + r0 + r) * DD + c0] =
            make_float4(acc[r][0], acc[r][1], acc[r][2], acc[r][3]);
}

// ---------------- Kernel 2: edges -> dedup'd CSR in one pass -------------
// atomicOr returns the OLD word: first setter of a bit owns the edge and
// appends col to the row's hit list. Duplicate (row,col) pairs are dropped,
// matching .at[row,col].set(1.0) semantics. List order is arbitrary (only
// affects fp summation order, within threshold).
__global__ void edge_kernel(const int* __restrict__ row, const int* __restrict__ col,
                            unsigned int* __restrict__ mask,
                            unsigned short* __restrict__ hits_g,
                            int* __restrict__ deg) {
    const int e = blockIdx.x * blockDim.x + threadIdx.x;
    if (e < NEDGES) {
        const int r = row[e], c = col[e];
        const unsigned int key = (unsigned int)r * NN + (unsigned int)c;
        const unsigned int bit = 1u << (key & 31u);
        const unsigned int old = atomicOr(&mask[key >> 5], bit);
        if (!(old & bit)) {
            const int slot = atomicAdd(&deg[r], 1);
            if (slot < CAPR) hits_g[r * CAPR + slot] = (unsigned short)c;
        }
    }
}

// ---------------- Kernel 3: fused score+softmax+aggregate ----------------
// 4 independent waves per block, one wave per (b,n) row. No LDS, no barriers.
// b = ((blk&7)<<1)|(wv&1): round-robin XCD mapping pins batches {2x,2x+1}
// (2 MB of z) in each XCD's 4 MB L2.
// Lane = (eq,hq): eq = edge slot 0..7, hq = dim-slice 0..7 (16 dims/lane).
// Live state: a[4]+v[4]+acc[4] = 48 VGPRs -> no spills (R4's 200 MB scratch
// traffic came from the 96-reg variant under a forced 128-reg cap).
__global__ void __launch_bounds__(256) gat_kernel(const float* __restrict__ z,
                                                  const unsigned short* __restrict__ hits_g,
                                                  const int* __restrict__ deg,
                                                  float* __restrict__ out) {
    const int tid = threadIdx.x, wv = tid >> 6, ln = tid & 63;
    const int blk = blockIdx.x;
    const int b = ((blk & 7) << 1) | (wv & 1);
    const int n = ((blk >> 3) << 1) | (wv >> 1);
    const int eq = ln >> 3, hq = ln & 7;

    const float* zb = z + ((size_t)b << 18);   // b*2048*128
    const int nh = min(deg[n], CAPR);
    const unsigned short* hrow = hits_g + n * CAPR;

    // this row's z slice (dims hq*16 .. hq*16+15) in registers
    float4 a[4];
    {
        const float4* znp = (const float4*)(zb + ((size_t)n << 7) + (hq << 4));
#pragma unroll
        for (int j = 0; j < 4; ++j) a[j] = znp[j];
    }

    float m = NEG_INF, l = 0.f;
    float4 acc[4];
#pragma unroll
    for (int j = 0; j < 4; ++j) acc[j] = make_float4(0.f, 0.f, 0.f, 0.f);

    for (int c0 = 0; c0 < nh; c0 += 8) {
        const int e = c0 + eq;
        const int he = hrow[min(e, nh - 1)];           // clamp pads in-bounds (L1 hit)
        const float4* zc = (const float4*)(zb + ((size_t)he << 7) + (hq << 4));
        float4 v[4];
#pragma unroll
        for (int j = 0; j < 4; ++j) v[j] = zc[j];

        float pt = 0.f;
#pragma unroll
        for (int j = 0; j < 4; ++j)
            pt += a[j].x * v[j].x + a[j].y * v[j].y + a[j].z * v[j].z + a[j].w * v[j].w;
        pt += __shfl_xor(pt, 1, 64);
        pt += __shfl_xor(pt, 2, 64);
        pt += __shfl_xor(pt, 4, 64);                   // full 128-dim dot in all hq lanes
        float sv = pt > 0.f ? pt : LEAK * pt;          // leaky_relu(0.1)
        if (sv == 0.f || e >= nh) sv = NEG_INF;        // masked_fill(att==0) / pad

        float mx = sv;
#pragma unroll
        for (int off = 8; off <= 32; off <<= 1) mx = fmaxf(mx, __shfl_xor(mx, off, 64));
        const float mnew = fmaxf(m, mx);
        const float alpha = __expf(m - mnew);          // 1 while m==mnew==NEG_INF
        const float pr = __expf(sv - mnew);            // 0 for pads once m is real
        float ps = pr;
#pragma unroll
        for (int off = 8; off <= 32; off <<= 1) ps += __shfl_xor(ps, off, 64);
        l = l * alpha + ps;
        m = mnew;
#pragma unroll
        for (int j = 0; j < 4; ++j) {
            acc[j].x = acc[j].x * alpha + pr * v[j].x;
            acc[j].y = acc[j].y * alpha + pr * v[j].y;
            acc[j].z = acc[j].z * alpha + pr * v[j].z;
            acc[j].w = acc[j].w * alpha + pr * v[j].w;
        }
    }

    if (nh > 0 && m > 0.5f * NEG_INF) {
        // sum acc across the 8 edge-lanes (xor bits 3..5), then normalize
#pragma unroll
        for (int off = 8; off <= 32; off <<= 1) {
#pragma unroll
            for (int j = 0; j < 4; ++j) {
                acc[j].x += __shfl_xor(acc[j].x, off, 64);
                acc[j].y += __shfl_xor(acc[j].y, off, 64);
                acc[j].z += __shfl_xor(acc[j].z, off, 64);
                acc[j].w += __shfl_xor(acc[j].w, off, 64);
            }
        }
        const float inv = 1.f / l;
#pragma unroll
        for (int j = 0; j < 4; ++j) {
            acc[j].x *= inv; acc[j].y *= inv; acc[j].z *= inv; acc[j].w *= inv;
        }
    } else {
        // no valid edge: softmax over uniform -1e16 row -> mean of z[b]
#pragma unroll
        for (int j = 0; j < 4; ++j) acc[j] = make_float4(0.f, 0.f, 0.f, 0.f);
        for (int mm = 0; mm < NN; ++mm) {
            const float4* zr = (const float4*)(zb + ((size_t)mm << 7) + (hq << 4));
#pragma unroll
            for (int j = 0; j < 4; ++j) {
                float4 t = zr[j];
                acc[j].x += t.x; acc[j].y += t.y; acc[j].z += t.z; acc[j].w += t.w;
            }
        }
#pragma unroll
        for (int j = 0; j < 4; ++j) {
            acc[j].x *= (1.f / NN); acc[j].y *= (1.f / NN);
            acc[j].z *= (1.f / NN); acc[j].w *= (1.f / NN);
        }
    }

    // store: lanes with eq<4 write float4 #eq of their hq slice (512 B/row)
    if (eq < 4) {
        float4 o = acc[0];
        if (eq == 1) o = acc[1];
        if (eq == 2) o = acc[2];
        if (eq == 3) o = acc[3];
        *(float4*)(out + (((size_t)b * NN + n) << 7) + (hq << 4) + (eq << 2)) = o;
    }
}

// ---------------- launcher ----------------
extern "C" void kernel_launch(void* const* d_in, const int* in_sizes, int n_in,
                              void* d_out, int out_size, void* d_ws, size_t ws_size,
                              hipStream_t stream) {
    const float* h = (const float*)d_in[0];
    const float* W = (const float*)d_in[1];
    const int* row = (const int*)d_in[2];
    const int* col = (const int*)d_in[3];
    float* out = (float*)d_out;

    char* ws = (char*)d_ws;
    float* z = (float*)ws;                                                     // 16 MB
    unsigned int* mask = (unsigned int*)(ws + (size_t)16 * 1024 * 1024);       // 512 KB
    unsigned short* hits_g = (unsigned short*)(ws + (size_t)16 * 1024 * 1024 + 512 * 1024); // 512 KB
    int* deg = (int*)(ws + (size_t)17 * 1024 * 1024);                          // 8 KB

    zgemm_kernel<<<(BC * NN) / 32, 256, 0, stream>>>(h, W, z, mask, deg);
    edge_kernel<<<NEDGES / 256, 256, 0, stream>>>(row, col, mask, hits_g, deg);
    gat_kernel<<<(BC * NN) / 4, 256, 0, stream>>>(z, hits_g, deg, out);
}